// Round 1
// baseline (660.011 us; speedup 1.0000x reference)
//
#include <hip/hip_runtime.h>

// LSTM decoder: B=1024 batch, H=16 hidden, 4H=64 gates, T=128 outer steps,
// 16 inner cells per step (window length A=16), R=128 input dim for h0/c0.
//
// Mapping: one wave (64 lanes) per batch element; lane j owns gate j.
//   - W_hh row j (16 floats) in registers per lane
//   - h[0..15] replicated in every lane's registers (so the 16-MAC gate dot
//     needs no cross-lane reduction)
//   - per cell: 3 shuffles to exchange i/f/g/o at k=j&15, then 16 shuffles
//     to rebroadcast new h. Everything else is in-register fp32 VALU.
// 1024 waves = 1 wave per SIMD across the whole chip.

#define B_ 1024
#define A_ 16
#define T_ 128
#define R_ 128
#define H_ 16

__global__ __launch_bounds__(64) void lstm_decoder_kernel(
    const float* __restrict__ y,     // (B,16)
    const float* __restrict__ u,     // (B,128)
    const float* __restrict__ W_ih,  // (64,1)
    const float* __restrict__ W_hh,  // (64,16)
    const float* __restrict__ b_ih,  // (64)
    const float* __restrict__ b_hh,  // (64)
    const float* __restrict__ W_lin, // (1,16)
    const float* __restrict__ b_lin, // (1)
    const float* __restrict__ W_h0,  // (16,128)
    const float* __restrict__ b_h0,  // (16)
    const float* __restrict__ W_c0,  // (16,128)
    const float* __restrict__ b_c0,  // (16)
    float* __restrict__ out)         // (B,144)
{
    const int b = blockIdx.x;     // batch element
    const int j = threadIdx.x;    // gate index 0..63
    const int k = j & 15;         // hidden index within gate group

    __shared__ float lds_u[R_];
    __shared__ float lds_h[H_];
    __shared__ float lds_c[H_];

    // ---- stage u[b,:] to LDS (coalesced) ----
    lds_u[j]      = u[b * R_ + j];
    lds_u[j + 64] = u[b * R_ + j + 64];
    __syncthreads();

    // ---- h0 / c0 init: lanes 0..15 compute h0[k], lanes 16..31 compute c0[k]
    if (j < 32) {
        const float* Wr = (j < 16) ? (W_h0 + k * R_) : (W_c0 + k * R_);
        float acc = (j < 16) ? b_h0[k] : b_c0[k];
        #pragma unroll
        for (int r = 0; r < R_; r += 4) {
            float4 wv = *(const float4*)(Wr + r);
            float4 uv = *(const float4*)(&lds_u[r]);
            acc = fmaf(wv.x, uv.x, acc);
            acc = fmaf(wv.y, uv.y, acc);
            acc = fmaf(wv.z, uv.z, acc);
            acc = fmaf(wv.w, uv.w, acc);
        }
        if (j < 16) lds_h[k] = acc;
        else        lds_c[k] = acc;
    }
    __syncthreads();

    // ---- per-lane register state ----
    float h[H_];
    #pragma unroll
    for (int m = 0; m < H_; ++m) h[m] = lds_h[m];
    float c = lds_c[k];

    float w[H_];   // W_hh row j
    {
        float4 r0 = *(const float4*)(W_hh + j * H_ + 0);
        float4 r1 = *(const float4*)(W_hh + j * H_ + 4);
        float4 r2 = *(const float4*)(W_hh + j * H_ + 8);
        float4 r3 = *(const float4*)(W_hh + j * H_ + 12);
        w[0]=r0.x; w[1]=r0.y; w[2]=r0.z; w[3]=r0.w;
        w[4]=r1.x; w[5]=r1.y; w[6]=r1.z; w[7]=r1.w;
        w[8]=r2.x; w[9]=r2.y; w[10]=r2.z; w[11]=r2.w;
        w[12]=r3.x; w[13]=r3.y; w[14]=r3.z; w[15]=r3.w;
    }
    const float bj = b_ih[j] + b_hh[j];
    const float wi = W_ih[j];          // (64,1) flat

    float wl[H_];
    #pragma unroll
    for (int m = 0; m < H_; ++m) wl[m] = W_lin[m];
    const float bl = b_lin[0];

    float win[A_];   // sliding window, replicated across lanes
    #pragma unroll
    for (int t = 0; t < A_; ++t) win[t] = y[b * A_ + t];

    const bool isg = ((j >> 4) == 2);  // lanes 32..47 hold the g (tanh) gate

    float pout0 = 0.f, pout1 = 0.f;    // preds for s==j and s==j+64

    for (int s = 0; s < T_; ++s) {
        #pragma unroll
        for (int t = 0; t < A_; ++t) {
            const float x = win[t];
            // gate_j = b_j + x*w_in_j + sum_k h[k]*W_hh[j,k]  (4 chains for ILP)
            float a0 = fmaf(x, wi, bj);
            a0 = fmaf(h[0], w[0], a0);
            float a1 = h[1] * w[1];
            float a2 = h[2] * w[2];
            float a3 = h[3] * w[3];
            #pragma unroll
            for (int m = 4; m < H_; m += 4) {
                a0 = fmaf(h[m + 0], w[m + 0], a0);
                a1 = fmaf(h[m + 1], w[m + 1], a1);
                a2 = fmaf(h[m + 2], w[m + 2], a2);
                a3 = fmaf(h[m + 3], w[m + 3], a3);
            }
            const float z = (a0 + a1) + (a2 + a3);
            // sigmoid for i,f,o lanes; tanh(z)=2*sigmoid(2z)-1 for g lanes
            const float z2 = isg ? (z + z) : z;
            const float e  = __expf(-z2);
            const float sg = __builtin_amdgcn_rcpf(1.0f + e);
            const float gv = isg ? fmaf(2.0f, sg, -1.0f) : sg;

            // exchange i,f,g,o for hidden index k
            const float iv = __shfl(gv, k,      64);
            const float fv = __shfl(gv, k + 16, 64);
            const float gg = __shfl(gv, k + 32, 64);
            const float ov = __shfl(gv, k + 48, 64);

            c = fmaf(fv, c, iv * gg);
            const float e2 = __expf(-2.0f * c);
            const float th = fmaf(2.0f, __builtin_amdgcn_rcpf(1.0f + e2), -1.0f);
            const float hk = ov * th;

            // rebroadcast h[0..15] to every lane
            #pragma unroll
            for (int m = 0; m < H_; ++m) h[m] = __shfl(hk, m, 64);
        }
        // pred = h . W_lin + b_lin (computed redundantly on all lanes)
        float p = bl;
        #pragma unroll
        for (int m = 0; m < H_; ++m) p = fmaf(h[m], wl[m], p);
        // slide window
        #pragma unroll
        for (int t = 0; t < A_ - 1; ++t) win[t] = win[t + 1];
        win[A_ - 1] = p;
        // stash pred for coalesced store at the end
        if (s == j)      pout0 = p;
        if (s == j + 64) pout1 = p;
    }

    // ---- output: out[b,0:16]=y[b,:], out[b,16+s]=pred_s ----
    if (j < A_) out[b * (A_ + T_) + j] = y[b * A_ + j];
    out[b * (A_ + T_) + A_ + j]      = pout0;
    out[b * (A_ + T_) + A_ + 64 + j] = pout1;
}

extern "C" void kernel_launch(void* const* d_in, const int* in_sizes, int n_in,
                              void* d_out, int out_size, void* d_ws, size_t ws_size,
                              hipStream_t stream) {
    const float* y     = (const float*)d_in[0];
    const float* u     = (const float*)d_in[1];
    const float* W_ih  = (const float*)d_in[2];
    const float* W_hh  = (const float*)d_in[3];
    const float* b_ih  = (const float*)d_in[4];
    const float* b_hh  = (const float*)d_in[5];
    const float* W_lin = (const float*)d_in[6];
    const float* b_lin = (const float*)d_in[7];
    const float* W_h0  = (const float*)d_in[8];
    const float* b_h0  = (const float*)d_in[9];
    const float* W_c0  = (const float*)d_in[10];
    const float* b_c0  = (const float*)d_in[11];
    float* out = (float*)d_out;

    lstm_decoder_kernel<<<B_, 64, 0, stream>>>(
        y, u, W_ih, W_hh, b_ih, b_hh, W_lin, b_lin,
        W_h0, b_h0, W_c0, b_c0, out);
}